// Round 3
// baseline (517.588 us; speedup 1.0000x reference)
//
#include <hip/hip_runtime.h>
#include <stdint.h>

// z: [16,1024,256] fp32 -> N=16384 rows, D=256
// embedding: [8192,256] fp32 -> K=8192 codes
// out = [ z_q (4194304 f32) | loss (1 f32) | indices (16384 as f32) ]
#define N_ROWS   16384
#define DIM      256
#define N_CODES  8192
#define ZQ_ELEMS 4194304

typedef _Float16 f16x8 __attribute__((ext_vector_type(8)));
typedef _Float16 f16x4 __attribute__((ext_vector_type(4)));
typedef float    f32x16 __attribute__((ext_vector_type(16)));
typedef unsigned long long u64;

// ---- workspace layout (bytes): e_tiled 8 MB | norms 32 KB | pkeys 4 MB ----
#define WS_ET  0
#define WS_NRM (8388608)
#define WS_PK  (8421376)
// z hi/lo f16 planes live in the d_out z_q region (exactly 16 MB), overwritten
// by vq_final after all reads complete (stream-ordered).

static __device__ __forceinline__ void glds16(const void* gsrc, void* ldst) {
    __builtin_amdgcn_global_load_lds(
        (const __attribute__((address_space(1))) unsigned int*)gsrc,
        (__attribute__((address_space(3))) unsigned int*)ldst,
        16, 0, 0);
}

static __device__ __forceinline__ u64 packkey(float d, int c) {
    unsigned int u = __float_as_uint(d);
    u ^= ((unsigned int)((int)u >> 31)) | 0x80000000u;   // monotone float map
    return ((u64)u << 32) | (unsigned int)c;             // min => (dist, then idx)
}

// ---------------- prep E: norms + fragment-major tiled f16 hi/lo ----------------
// et layout (16-B units): slab(p,dk,f) = p*32 + dk*4 + f; unit addr = slab*8192 + code.
// f = which 8-half group of the code's dk-chunk (k = dk*32 + f*8 .. +8).
__global__ void vq_prep_e(const float* __restrict__ emb,
                          _Float16* __restrict__ et,
                          float* __restrict__ norms, float* __restrict__ loss_ptr) {
    if (blockIdx.x == 0 && threadIdx.x == 0) *loss_ptr = 0.0f;
    __shared__ _Float16 lh[4][256];
    __shared__ _Float16 ll[4][256];
    const int t = threadIdx.x, w = t >> 6, l = t & 63;
    const int code = blockIdx.x * 4 + w;
    float4 v = *(const float4*)(emb + (size_t)code * DIM + l * 4);
    float xs[4] = {v.x, v.y, v.z, v.w};
    f16x4 hh, lo;
    float s = 0.0f;
    #pragma unroll
    for (int i = 0; i < 4; ++i) {
        _Float16 h = (_Float16)xs[i];
        hh[i] = h;
        lo[i] = (_Float16)(xs[i] - (float)h);
        s += xs[i] * xs[i];
    }
    *(f16x4*)&lh[w][l * 4] = hh;
    *(f16x4*)&ll[w][l * 4] = lo;
    #pragma unroll
    for (int off = 32; off > 0; off >>= 1) s += __shfl_down(s, off, 64);
    if (l == 0) norms[code] = s;
    __syncthreads();
    // phase 2: 256 threads write 256 16-B groups (2 planes x 4 codes x 8 dk x 4 f)
    const int p = t >> 7, g = t & 127;
    const int cl = g & 3, dk = (g >> 2) & 7, f = g >> 5;
    f16x8 frag = (p == 0) ? *(const f16x8*)&lh[cl][dk * 32 + f * 8]
                          : *(const f16x8*)&ll[cl][dk * 32 + f * 8];
    const size_t slab = (size_t)(p * 32 + dk * 4 + f);
    *(f16x8*)(et + (slab * N_CODES + blockIdx.x * 4 + cl) * 8) = frag;
}

// ---------------- prep Z: natural-layout f16 hi/lo planes (into zq region) ----------------
__global__ void vq_prep_z(const float* __restrict__ z,
                          _Float16* __restrict__ zh, _Float16* __restrict__ zl) {
    int gt = blockIdx.x * 256 + threadIdx.x;
    int row = gt >> 6, lane = gt & 63;
    float4 v = *(const float4*)(z + (size_t)row * DIM + lane * 4);
    float xs[4] = {v.x, v.y, v.z, v.w};
    f16x4 hh, lo;
    #pragma unroll
    for (int i = 0; i < 4; ++i) {
        _Float16 h = (_Float16)xs[i];
        hh[i] = h;
        lo[i] = (_Float16)(xs[i] - (float)h);
    }
    *(f16x4*)(zh + (size_t)row * DIM + lane * 4) = hh;
    *(f16x4*)(zl + (size_t)row * DIM + lane * 4) = lo;
}

// ---------------- main: 128 rows x 256 codes per block, glds dbuf ----------------
// grid 4096 = 128 row-blocks x 32 code-blocks. 4 waves; wave tile 128x64 (4rt x 2ct).
// LDS: 2 x 32768 B buffers; buffer = [p(2)][f(4)][code(256)] 16-B units.
__global__ __launch_bounds__(256, 2)
void vq_main(const _Float16* __restrict__ zh, const _Float16* __restrict__ zl,
             const _Float16* __restrict__ et, const float* __restrict__ norms,
             u64* __restrict__ pkeys) {
    extern __shared__ char smem[];
    const int tid = threadIdx.x;
    const int w = tid >> 6, L = tid & 63, lo5 = L & 31, hi1 = L >> 5;
    const int rb = blockIdx.x & 127;      // 128 consecutive blocks share a code window
    const int cb = blockIdx.x >> 7;
    const int row0 = rb * 128;
    const int code0 = cb * 256;
    const int idx0 = w * 8;

    f32x16 acc[4][2];
    #pragma unroll
    for (int rt = 0; rt < 4; ++rt)
        #pragma unroll
        for (int ct = 0; ct < 2; ++ct)
            #pragma unroll
            for (int e = 0; e < 16; ++e) acc[rt][ct][e] = 0.0f;

    // stage dk=0 into buf 0: 32 glds of 1 KB across 4 waves
    #pragma unroll
    for (int i = 0; i < 8; ++i) {
        const int idx = idx0 + i;
        const int pbit = idx >> 4, f2 = (idx >> 2) & 3, s2 = idx & 3;
        const _Float16* g = et + ((size_t)(pbit * 32 + 0 * 4 + f2) * N_CODES
                                  + code0 + s2 * 64 + L) * 8;
        glds16(g, smem + idx * 1024);
    }

    for (int dk = 0; dk < 8; ++dk) {
        __syncthreads();                       // staging of buf[dk&1] complete
        if (dk < 7) {                          // prefetch dk+1 into other buffer
            char* nbuf = smem + ((dk + 1) & 1) * 32768;
            #pragma unroll
            for (int i = 0; i < 8; ++i) {
                const int idx = idx0 + i;
                const int pbit = idx >> 4, f2 = (idx >> 2) & 3, s2 = idx & 3;
                const _Float16* g = et + ((size_t)(pbit * 32 + (dk + 1) * 4 + f2) * N_CODES
                                          + code0 + s2 * 64 + L) * 8;
                glds16(g, nbuf + idx * 1024);
            }
        }
        const char* buf = smem + (dk & 1) * 32768;

        #pragma unroll
        for (int ks = 0; ks < 2; ++ks) {
            const int koff = dk * 32 + ks * 16 + hi1 * 8;
            f16x8 ah[4], al[4];
            #pragma unroll
            for (int rt = 0; rt < 4; ++rt) {
                const int r = row0 + rt * 32 + lo5;
                ah[rt] = *(const f16x8*)(zh + r * DIM + koff);
                al[rt] = *(const f16x8*)(zl + r * DIM + koff);
            }
            f16x8 bh[2], bl[2];
            const int f = ks * 2 + hi1;
            #pragma unroll
            for (int ct = 0; ct < 2; ++ct) {
                const int off = f * 4096 + (w * 64 + ct * 32 + lo5) * 16;
                bh[ct] = *(const f16x8*)(buf + off);
                bl[ct] = *(const f16x8*)(buf + 16384 + off);
            }
            #pragma unroll
            for (int rt = 0; rt < 4; ++rt)
                #pragma unroll
                for (int ct = 0; ct < 2; ++ct) {
                    acc[rt][ct] = __builtin_amdgcn_mfma_f32_32x32x16_f16(ah[rt], bh[ct], acc[rt][ct], 0, 0, 0);
                    acc[rt][ct] = __builtin_amdgcn_mfma_f32_32x32x16_f16(ah[rt], bl[ct], acc[rt][ct], 0, 0, 0);
                    acc[rt][ct] = __builtin_amdgcn_mfma_f32_32x32x16_f16(al[rt], bh[ct], acc[rt][ct], 0, 0, 0);
                }
        }
    }

    // ---- argmin: pack (dist, code) -> u64, butterfly over 32 code-lanes ----
    __syncthreads();                           // all frag reads done; reuse LDS
    u64* sc = (u64*)smem;                      // [4][128]
    const int cbase = code0 + w * 64 + lo5;
    const float nrm0 = norms[cbase];
    const float nrm1 = norms[cbase + 32];
    #pragma unroll
    for (int rt = 0; rt < 4; ++rt)
        #pragma unroll
        for (int reg = 0; reg < 16; ++reg) {
            u64 k0 = packkey(nrm0 - 2.0f * acc[rt][0][reg], cbase);
            u64 k1 = packkey(nrm1 - 2.0f * acc[rt][1][reg], cbase + 32);
            u64 k = (k1 < k0) ? k1 : k0;
            u64 o;
            o = __shfl_xor(k, 1, 64);  if (o < k) k = o;
            o = __shfl_xor(k, 2, 64);  if (o < k) k = o;
            o = __shfl_xor(k, 4, 64);  if (o < k) k = o;
            o = __shfl_xor(k, 8, 64);  if (o < k) k = o;
            o = __shfl_xor(k, 16, 64); if (o < k) k = o;
            if (lo5 == 0) {
                const int rloc = rt * 32 + (reg & 3) + ((reg >> 2) << 3) + (hi1 << 2);
                sc[w * 128 + rloc] = k;
            }
        }
    __syncthreads();
    if (tid < 128) {
        u64 k = sc[tid];
        #pragma unroll
        for (int w2 = 1; w2 < 4; ++w2) { u64 o = sc[w2 * 128 + tid]; if (o < k) k = o; }
        pkeys[(size_t)cb * N_ROWS + row0 + tid] = k;
    }
}

// ---------------- final: merge 32 partials, idx, z_q gather, loss ----------------
__global__ __launch_bounds__(512)
void vq_final(const float* __restrict__ z, const float* __restrict__ emb,
              const u64* __restrict__ pkeys,
              float* __restrict__ zq_out, float* __restrict__ loss_out,
              float* __restrict__ idx_out) {
    __shared__ u64 kk[8][64];
    __shared__ int best[64];
    const int t = threadIdx.x;
    const int row0 = blockIdx.x * 64;
    const int r = t & 63, j = t >> 6;
    u64 k = ~0ULL;
    #pragma unroll
    for (int q = 0; q < 4; ++q) {
        u64 o = pkeys[(size_t)(j * 4 + q) * N_ROWS + row0 + r];
        if (o < k) k = o;
    }
    kk[j][r] = k;
    __syncthreads();
    if (t < 64) {
        u64 kb = kk[0][t];
        #pragma unroll
        for (int j2 = 1; j2 < 8; ++j2) if (kk[j2][t] < kb) kb = kk[j2][t];
        int code = (int)(kb & 0xFFFFFFFFu);
        best[t] = code;
        idx_out[row0 + t] = (float)code;
    }
    __syncthreads();
    const int wave = t >> 6, lane = t & 63;
    float lsum = 0.0f;
    #pragma unroll
    for (int rr = 0; rr < 8; ++rr) {
        const int rl = wave * 8 + rr;
        const int rg = row0 + rl;
        const int code = best[rl];
        float4 ev = *(const float4*)(emb + (size_t)code * DIM + lane * 4);
        float4 zv = *(const float4*)(z   + (size_t)rg   * DIM + lane * 4);
        float dx = ev.x - zv.x, dy = ev.y - zv.y;
        float dz = ev.z - zv.z, dw = ev.w - zv.w;
        lsum += dx * dx + dy * dy + dz * dz + dw * dw;
        *(float4*)(zq_out + (size_t)rg * DIM + lane * 4) = ev;
    }
    #pragma unroll
    for (int off = 32; off > 0; off >>= 1) lsum += __shfl_down(lsum, off, 64);
    if (lane == 0) atomicAdd(loss_out, lsum * (1.25f / (float)ZQ_ELEMS));
}

extern "C" void kernel_launch(void* const* d_in, const int* in_sizes, int n_in,
                              void* d_out, int out_size, void* d_ws, size_t ws_size,
                              hipStream_t stream) {
    const float* z   = (const float*)d_in[0];
    const float* emb = (const float*)d_in[1];
    float* out  = (float*)d_out;
    float* zq   = out;
    float* loss = out + ZQ_ELEMS;
    float* idx  = out + ZQ_ELEMS + 1;

    char* ws = (char*)d_ws;
    _Float16* et = (_Float16*)(ws + WS_ET);
    float* norms = (float*)(ws + WS_NRM);
    u64*   pk    = (u64*)(ws + WS_PK);

    // z f16 planes parked in the z_q output region (16 MB, exact fit);
    // vq_final overwrites it after all reads are done.
    _Float16* zh = (_Float16*)zq;
    _Float16* zl = zh + (size_t)N_ROWS * DIM;

    static bool attr_set = false;
    if (!attr_set) {
        hipFuncSetAttribute((const void*)vq_main,
                            hipFuncAttributeMaxDynamicSharedMemorySize, 65536);
        attr_set = true;
    }

    vq_prep_e<<<N_CODES / 4, 256, 0, stream>>>(emb, et, norms, loss);
    vq_prep_z<<<N_ROWS / 4, 256, 0, stream>>>(z, zh, zl);
    vq_main<<<4096, 256, 65536, stream>>>(zh, zl, et, norms, pk);
    vq_final<<<N_ROWS / 64, 512, 0, stream>>>(z, emb, pk, zq, loss, idx);
}